// Round 18
// baseline (37.654 us; speedup 1.0000x reference)
//
#include <hip/hip_runtime.h>
#include <math.h>

#define HH 2048
#define WW 2048
#define TB 4
#define NBLK 1024

// Gaussian sigma=2, 5 taps, normalized
#define GW0 0.15246914402033867f
#define GW1 0.22184129554377693f
#define GW2 0.25137912086578894f

typedef float f4 __attribute__((ext_vector_type(4)));

struct R8 { float v[8]; };
struct R6 { float v[6]; };

__device__ __forceinline__ int reflect_row(int vr) {
    return vr < 0 ? -vr : (vr >= HH ? 2 * HH - 2 - vr : vr);
}

// ======================= Kernel A: separable gaussian -> blur (ws) =======================
// h row 4-wide (own cols) from lab row r with x-reflect; window x = xb-2 .. xb+5 via 2 f4.
__device__ __forceinline__ f4 hrow4(const float* __restrict__ lab, int r, int xb,
                                    bool edgew, bool le, bool re) {
    const float* row = lab + (size_t)r * WW;
    f4 A = *(const f4*)(row + max(xb - 2, 0));
    f4 B = *(const f4*)(row + min(xb + 2, WW - 4));
    float w[8] = {A.x, A.y, A.z, A.w, B.x, B.y, B.z, B.w};
    if (edgew) {
        if (le) { w[0] = A.z; w[1] = A.y; w[2] = A.x; w[3] = A.y; }  // reflect: [-2,-1,0,1]->[l2,l1,l0,l1]
        if (re) { w[4] = B.z; w[5] = B.w; w[6] = B.z; w[7] = B.y; }  // [2046,2047,2046,2045]
    }
    f4 h;
    h.x = GW0 * (w[0] + w[4]) + GW1 * (w[1] + w[3]) + GW2 * w[2];
    h.y = GW0 * (w[1] + w[5]) + GW1 * (w[2] + w[4]) + GW2 * w[3];
    h.z = GW0 * (w[2] + w[6]) + GW1 * (w[3] + w[5]) + GW2 * w[4];
    h.w = GW0 * (w[3] + w[7]) + GW1 * (w[4] + w[6]) + GW2 * w[5];
    return h;
}

__global__ __launch_bounds__(256) void steal_blur(const float* __restrict__ lab,
                                                  float* __restrict__ blur) {
    const int lane = threadIdx.x & 63;
    const int xcd   = blockIdx.x & 7;
    const int idx   = blockIdx.x >> 3;
    const int local = (idx << 2) + (threadIdx.x >> 6);     // 0..511 within XCD
    const int sx = local & 7;
    const int rg = (xcd << 6) + (local >> 3);              // XCD k owns rows [256k, 256k+256)
    const int y0 = rg * TB;
    const int xb = sx * 256 + lane * 4;
    const bool edgew = (sx == 0) || (sx == 7);
    const bool le = (sx == 0) && (lane == 0);
    const bool re = (sx == 7) && (lane == 63);

    f4 h0 = hrow4(lab, reflect_row(y0 - 2), xb, edgew, le, re);
    f4 h1 = hrow4(lab, reflect_row(y0 - 1), xb, edgew, le, re);
    f4 h2 = hrow4(lab, y0 + 0, xb, edgew, le, re);
    f4 h3 = hrow4(lab, y0 + 1, xb, edgew, le, re);

    #pragma unroll
    for (int i = 0; i < TB; ++i) {
        f4 h4 = hrow4(lab, reflect_row(y0 + i + 2), xb, edgew, le, re);
        f4 bl = GW0 * (h0 + h4) + GW1 * (h1 + h3) + GW2 * h2;
        *(f4*)(blur + (size_t)(y0 + i) * WW + xb) = bl;
        h0 = h1; h1 = h2; h2 = h3; h3 = h4;
    }
}

// ======================= Kernel B: blur + pred -> loss partials =======================
// blur window 8-wide (x = xb-2 .. xb+5) with x-REPLICATE pad
__device__ __forceinline__ R8 bload(const float* __restrict__ blur, int r, int xb,
                                    bool edgew, bool le, bool re) {
    const float* row = blur + (size_t)r * WW;
    f4 A = *(const f4*)(row + max(xb - 2, 0));
    f4 B = *(const f4*)(row + min(xb + 2, WW - 4));
    R8 o;
    o.v[0] = A.x; o.v[1] = A.y; o.v[2] = A.z; o.v[3] = A.w;
    o.v[4] = B.x; o.v[5] = B.y; o.v[6] = B.z; o.v[7] = B.w;
    if (edgew) {
        if (le) { o.v[1] = A.x; o.v[2] = A.x; o.v[3] = A.y; }   // [b0,b0,b0,b1,...]
        if (re) { o.v[4] = B.z; o.v[5] = B.w; o.v[6] = B.w; o.v[7] = B.w; }  // [...,2046,2047,2047,2047]
    }
    return o;
}

// e = exp(pred*10) window 8-wide, zero outside image (x and y), EXACT edge mapping
__device__ __forceinline__ R8 eload(const float* __restrict__ pred, int r, int xb,
                                    bool zrow, bool edgew, bool le, bool re) {
    R8 o;
    if (zrow) {
        #pragma unroll
        for (int j = 0; j < 8; ++j) o.v[j] = 0.f;
        return o;
    }
    const float* row = pred + (size_t)r * WW;
    f4 A = *(const f4*)(row + max(xb - 2, 0));
    f4 B = *(const f4*)(row + min(xb + 2, WW - 4));
    float w[8] = {A.x, A.y, A.z, A.w, B.x, B.y, B.z, B.w};
    if (edgew) {
        if (le) { w[2] = A.x; w[3] = A.y; }                 // [.,.,p0,p1,...]
        if (re) { w[4] = B.z; w[5] = B.w; }                 // [...,p2046,p2047,.,.]
    }
    #pragma unroll
    for (int j = 0; j < 8; ++j) o.v[j] = __expf(w[j] * 10.f);
    if (edgew) {
        if (le) { o.v[0] = 0.f; o.v[1] = 0.f; }
        if (re) { o.v[6] = 0.f; o.v[7] = 0.f; }
    }
    return o;
}

// first sobel: 8-wide blur rows -> 6-wide gx,gy (x = xb-1 .. xb+4), x-clamp dup on edges
__device__ __forceinline__ void sobel(const R8& u, const R8& m, const R8& d, R6& ox, R6& oy,
                                      bool edgew, bool le, bool re) {
    #pragma unroll
    for (int j = 0; j < 6; ++j) {
        ox.v[j] = ((u.v[j+2] - u.v[j]) + 2.f*(m.v[j+2] - m.v[j]) + (d.v[j+2] - d.v[j])) * 0.125f;
        oy.v[j] = ((d.v[j] - u.v[j]) + 2.f*(d.v[j+1] - u.v[j+1]) + (d.v[j+2] - u.v[j+2])) * 0.125f;
    }
    if (edgew) {
        if (le) { ox.v[0] = ox.v[1]; oy.v[0] = oy.v[1]; }
        if (re) { ox.v[5] = ox.v[4]; oy.v[5] = oy.v[4]; }
    }
}

__global__ __launch_bounds__(256) void steal_main(const float* __restrict__ pred,
                                                  const float* __restrict__ blur,
                                                  float* __restrict__ acc) {
    __shared__ float s_red[4];
    const int lane = threadIdx.x & 63;
    const int xcd   = blockIdx.x & 7;
    const int idx   = blockIdx.x >> 3;
    const int local = (idx << 2) + (threadIdx.x >> 6);     // 0..511 within XCD
    const int sx = local & 7;
    const int rg = (xcd << 6) + (local >> 3);              // aligned bands with kernel A
    const int y0 = rg * TB;
    const int xb = sx * 256 + lane * 4;
    const bool edgew = (sx == 0) || (sx == 7);
    const bool le = (sx == 0) && (lane == 0);
    const bool re = (sx == 7) && (lane == 63);

    const float T1f = 0.41421356237309503f;   // tan(pi/8)
    const float T3f = 2.41421356237309510f;   // tan(3pi/8)

    // ---------------- prime: blur rows + first-sobel rows ----------------
    R8 b0, b1;
    R6 gx0, gy0, gx1, gy1;
    {
        b0 = bload(blur, y0 + 0, xb, edgew, le, re);
        b1 = bload(blur, y0 + 1, xb, edgew, le, re);
        if (y0 > 0) {
            R8 bm2 = bload(blur, y0 - 2, xb, edgew, le, re);
            R8 bm1 = bload(blur, y0 - 1, xb, edgew, le, re);
            sobel(bm2, bm1, b0, gx0, gy0, edgew, le, re);  // gxgy[y0-1]
            sobel(bm1, b0,  b1, gx1, gy1, edgew, le, re);  // gxgy[y0]
        } else {
            sobel(b0, b0, b1, gx1, gy1, edgew, le, re);    // gxgy[0] (row replicate)
            gx0 = gx1; gy0 = gy1;
        }
    }

    // ---------------- prime e window rows y0-2 .. y0+1 ----------------
    R8 e0 = eload(pred, max(y0 - 2, 0), xb, (y0 - 2 < 0), edgew, le, re);
    R8 e1 = eload(pred, max(y0 - 1, 0), xb, (y0 - 1 < 0), edgew, le, re);
    R8 e2 = eload(pred, y0 + 0, xb, false, edgew, le, re);
    R8 e3 = eload(pred, y0 + 1, xb, false, edgew, le, re);

    float lsum = 0.f;

    for (int i = 0; i < TB; ++i) {
        const int y = y0 + i;

        R8 bn = (y + 2 < HH) ? bload(blur, y + 2, xb, edgew, le, re) : b1;  // row replicate

        R6 gxn, gyn;                                       // gxgy[y+1]
        if (y + 1 < HH) sobel(b0, b1, bn, gxn, gyn, edgew, le, re);
        else { gxn = gx1; gyn = gy1; }

        R8 en = eload(pred, min(y + 2, HH - 1), xb, (y + 2 >= HH), edgew, le, re);

        #pragma unroll
        for (int k = 0; k < 4; ++k) {
            float gxx = ((gx0.v[k+2]-gx0.v[k]) + 2.f*(gx1.v[k+2]-gx1.v[k]) +
                         (gxn.v[k+2]-gxn.v[k])) * 0.125f;
            float gxy = ((gy0.v[k+2]-gy0.v[k]) + 2.f*(gy1.v[k+2]-gy1.v[k]) +
                         (gyn.v[k+2]-gyn.v[k])) * 0.125f;
            float gyy = ((gyn.v[k]-gy0.v[k]) + 2.f*(gyn.v[k+1]-gy0.v[k+1]) +
                         (gyn.v[k+2]-gy0.v[k+2])) * 0.125f;
            float sg = -(gxy + 1e-6f);
            float sgn = (sg > 0.f) ? 1.f : ((sg < 0.f) ? -1.f : 0.f);
            float rt = gyy * sgn * __builtin_amdgcn_rcpf(gxx + 1e-6f);

            float hs  = e2.v[k] + e2.v[k+1] + e2.v[k+2] + e2.v[k+3] + e2.v[k+4];
            float vs  = e0.v[k+2] + e1.v[k+2] + e2.v[k+2] + e3.v[k+2] + en.v[k+2];
            float dls = e0.v[k]   + e1.v[k+1] + e2.v[k+2] + e3.v[k+3] + en.v[k+4];
            float dcs = e0.v[k+4] + e1.v[k+3] + e2.v[k+2] + e3.v[k+1] + en.v[k];

            bool isH = (rt >= -T1f) && (rt < T1f);
            bool isL = (rt >=  T1f) && (rt < T3f);
            bool isC = (rt >= -T3f) && (rt < -T1f);
            bool has = isH || isL || isC || (rt >= T3f) || (rt < -T3f);  // false only for NaN
            float resp = isH ? hs : (isL ? dls : (isC ? dcs : vs));
            float lv = __logf(e2.v[k + 2]) - __logf(resp + 1e-6f);       // log(exp(pc*10)) = pc*10
            lsum += has ? lv : 0.f;
        }

        b0 = b1; b1 = bn;
        gx0 = gx1; gx1 = gxn; gy0 = gy1; gy1 = gyn;
        e0 = e1; e1 = e2; e2 = e3; e3 = en;
    }

    // ---------------- block reduction (wave = 64) ----------------
    float v = lsum;
    #pragma unroll
    for (int off = 32; off; off >>= 1) v += __shfl_down(v, off, 64);
    if ((threadIdx.x & 63) == 0) s_red[threadIdx.x >> 6] = v;
    __syncthreads();
    if (threadIdx.x == 0) {
        acc[blockIdx.x] = s_red[0] + s_red[1] + s_red[2] + s_red[3];
    }
}

__global__ __launch_bounds__(256) void steal_finalize(const float* __restrict__ acc,
                                                      float* __restrict__ out, int n) {
    __shared__ double sd[256];
    double a = 0.0;
    int n4 = n >> 2;
    for (int i = threadIdx.x; i < n4; i += 256) {
        f4 v = *(const f4*)(acc + i * 4);
        a += (double)v.x + (double)v.y + (double)v.z + (double)v.w;
    }
    for (int i = (n4 << 2) + threadIdx.x; i < n; i += 256) a += (double)acc[i];
    sd[threadIdx.x] = a;
    __syncthreads();
    for (int s = 128; s > 0; s >>= 1) {
        if (threadIdx.x < s) sd[threadIdx.x] += sd[threadIdx.x + s];
        __syncthreads();
    }
    if (threadIdx.x == 0) out[0] = (float)(-sd[0] / 4194304.0);
}

extern "C" void kernel_launch(void* const* d_in, const int* in_sizes, int n_in,
                              void* d_out, int out_size, void* d_ws, size_t ws_size,
                              hipStream_t stream) {
    const float* pred = (const float*)d_in[0];   // (1,1,2048,2048) f32
    const float* lab  = (const float*)d_in[1];   // (1,2048,2048) f32
    float* out = (float*)d_out;                  // scalar f32

    float* blur = (float*)d_ws;                                  // 16 MB
    float* acc  = (float*)((char*)d_ws + (size_t)HH * WW * 4);   // 4 KB partials

    steal_blur<<<NBLK, 256, 0, stream>>>(lab, blur);
    steal_main<<<NBLK, 256, 0, stream>>>(pred, blur, acc);
    steal_finalize<<<1, 256, 0, stream>>>(acc, out, NBLK);
}